// Round 4
// baseline (902.455 us; speedup 1.0000x reference)
//
#include <hip/hip_runtime.h>
#include <hip/hip_fp16.h>

#define LDIM 50
#define MBIN 262144
#define ODIM 155
#define VOCABSZ 100

// workspace layout — produced by precompute_kernel
// half-indexed (from (const __half*)ws):
#define H_T   0       // 30000 : T[s][v][d] fp16, s=0 pe-slot (b_pred folded), s=1..5 ve-slots
#define H_PE  30000   // 5000  : pe fp16
#define H_VE  35000   // 5000  : ve fp16
#define H_TB  40000   // 5000  : (oe@W_bin[50:100]+b_bin) fp16
#define H_OE  45000   // 5000  : oe fp16
// float-indexed (from (float*)ws):
#define F_LG  25000   // 300 : attention logits fp32  [0..99]=pe, [100..199]=ve, [200..299]=oe

// static-LDS layout for fused kernel: 20304 floats = 81216 B => 2 blocks/CU = 16 waves/CU
// half-offsets into ldsh:
//   [0..30000)     T fp16          (post-phase1: hA fp16 stash [25][512]; phase3: transpose overlay)
//   [30000..35000) pe fp16         (phase2: Tb fp16)
//   [35000..40000) ve fp16         (phase2: oe fp16)
//   [40000..40608) lg fp32 (304 floats at float-offset 20000)
#define LDS_FLOATS 20304

// ---------------------------------------------------------------------------
// Precompute vocab-indexed tables (trivial cost) — fp16 tables + fp32 logits
// ---------------------------------------------------------------------------
__global__ __launch_bounds__(64) void precompute_kernel(
    const float* __restrict__ pe, const float* __restrict__ ve, const float* __restrict__ oe,
    const float* __restrict__ W_pred, const float* __restrict__ b_pred,
    const float* __restrict__ W_bin, const float* __restrict__ b_bin,
    const float* __restrict__ W_att, const float* __restrict__ b_att,
    float* __restrict__ ws)
{
    __half* wsh = (__half*)ws;
    const int bid = blockIdx.x;
    const int t = threadIdx.x;
    if (bid < 600) {                    // T tables
        const int s = bid / VOCABSZ, v = bid % VOCABSZ;
        if (t < LDIM) {
            const float* E = (s == 0) ? pe : ve;
            float acc = (s == 0) ? b_pred[t] : 0.0f;
            for (int e = 0; e < LDIM; ++e)
                acc += E[v*LDIM + e] * W_pred[(s*LDIM + e)*LDIM + t];
            wsh[H_T + (s*VOCABSZ + v)*LDIM + t] = __float2half_rn(acc);
        }
    } else if (bid < 700) {             // Tb = oe @ W_bin[50:100] + b_bin
        const int v = bid - 600;
        if (t < LDIM) {
            float acc = b_bin[t];
            for (int e = 0; e < LDIM; ++e)
                acc += oe[v*LDIM + e] * W_bin[(LDIM + e)*LDIM + t];
            wsh[H_TB + v*LDIM + t] = __float2half_rn(acc);
        }
    } else if (bid < 800) {             // pe copy -> fp16
        const int v = bid - 700;
        if (t < LDIM) wsh[H_PE + v*LDIM + t] = __float2half_rn(pe[v*LDIM + t]);
    } else if (bid < 900) {             // ve copy -> fp16
        const int v = bid - 800;
        if (t < LDIM) wsh[H_VE + v*LDIM + t] = __float2half_rn(ve[v*LDIM + t]);
    } else if (bid < 1000) {            // oe copy -> fp16
        const int v = bid - 900;
        if (t < LDIM) wsh[H_OE + v*LDIM + t] = __float2half_rn(oe[v*LDIM + t]);
    } else {                            // attention logits (fp32)
        const int g = (bid - 1000)*64 + t;
        if (g < 300) {
            const int which = g / VOCABSZ, v = g % VOCABSZ;
            const float* E = (which == 0) ? pe : ((which == 1) ? ve : oe);
            float acc = b_att[0];
            for (int e = 0; e < LDIM; ++e)
                acc += E[v*LDIM + e] * W_att[e];
            ws[F_LG + g] = acc;
        }
    }
}

// ---------------------------------------------------------------------------
// Build h_pred for node (p, v[5]) from fp16 LDS tables. Returns exp(h.W_att+b).
// ---------------------------------------------------------------------------
__device__ __forceinline__ float build_pred_node_h(
    int p, const int* v, const __half* __restrict__ ldsh, const float* __restrict__ lg,
    const float* __restrict__ W_att, float batt, float* __restrict__ hout)
{
    const float e0 = __expf(lg[p]);
    float ek[5];
    float den = e0;
#pragma unroll
    for (int s = 0; s < 5; ++s) { ek[s] = __expf(lg[VOCABSZ + v[s]]); den += ek[s]; }
    const float inv = 1.0f / den;

    const __half2* T2  = (const __half2*)ldsh;
    const __half2* pe2 = (const __half2*)(ldsh + 30000);
    const __half2* ve2 = (const __half2*)(ldsh + 35000);
    const int rT0 = p*(LDIM/2);
    int rTs[5], rVs[5];
#pragma unroll
    for (int s = 0; s < 5; ++s) {
        rTs[s] = ((s+1)*VOCABSZ + v[s])*(LDIM/2);
        rVs[s] = v[s]*(LDIM/2);
    }

    float l = batt;
#pragma unroll
    for (int i = 0; i < LDIM/2; ++i) {
        float2 lin = __half22float2(T2[rT0 + i]);
        float2 pv  = __half22float2(pe2[rT0 + i]);
        float nx = e0*pv.x, ny = e0*pv.y;
#pragma unroll
        for (int s = 0; s < 5; ++s) {
            float2 a = __half22float2(T2[rTs[s] + i]);
            float2 b = __half22float2(ve2[rVs[s] + i]);
            lin.x += a.x; lin.y += a.y;
            nx += ek[s]*b.x; ny += ek[s]*b.y;
        }
        float hx = fmaxf(lin.x, 0.0f) + nx*inv;
        float hy = fmaxf(lin.y, 0.0f) + ny*inv;
        hout[2*i] = hx; hout[2*i+1] = hy;
        l += hx*W_att[2*i] + hy*W_att[2*i+1];
    }
    return __expf(l);
}

// ---------------------------------------------------------------------------
// Fused kernel: one thread per binary node. 81216 B static LDS => 2 blocks/CU
// = 16 waves/CU (vs 8 before). hA is stashed to LDS (fp16) after phase 1 so
// phase-2 live set is hB[50]+lin2[50] (~112) -> fits the allocator's hard
// 128-VGPR choice with NO spills (rounds 0-3 lesson: allocator pins 128 at
// 512-thr; the 150-float live set must be restructured, not flagged away).
// ---------------------------------------------------------------------------
__global__ __launch_bounds__(512)
void fused_kernel(
    const float* __restrict__ W_bin,
    const float* __restrict__ W_un, const float* __restrict__ b_un,
    const float* __restrict__ W_univ, const float* __restrict__ b_univ,
    const float* __restrict__ W_att, const float* __restrict__ b_att,
    const float* __restrict__ W_fin, const float* __restrict__ b_fin,
    const int* __restrict__ pred_ids, const int* __restrict__ var_ids,
    const int* __restrict__ op_ids,
    const float* __restrict__ ws, float* __restrict__ out)
{
    __shared__ float ldsf[LDS_FLOATS];          // 81216 B
    __half* ldsh = (__half*)ldsf;
    float* lgl = ldsf + 20000;                  // 304 floats
    const int tid = threadIdx.x;
    const int j = blockIdx.x * 512 + tid;

    // ---- stage T+pe+ve (fp16, contiguous 80000 B) + lg into LDS ----
    {
        const uint4* src = (const uint4*)ws;            // halves [0..40000) = 5000 uint4
        uint4* dst = (uint4*)ldsh;
        for (int i = tid; i < 5000; i += 512) dst[i] = src[i];
        if (tid < 300) lgl[tid] = ws[F_LG + tid];
    }
    __syncthreads();

    const float batt = b_att[0];

    // ---- phase 1: build both predicate nodes (regs) ----
    int vA[5], vB[5];
    const int pA = pred_ids[2*j], pB = pred_ids[2*j+1];
#pragma unroll
    for (int s = 0; s < 5; ++s) { vA[s] = var_ids[(2*j)*5 + s]; vB[s] = var_ids[(2*j+1)*5 + s]; }

    float hA[LDIM], hB[LDIM];
    const float w0 = build_pred_node_h(pA, vA, ldsh, lgl, W_att, batt, hA);
    const float w2 = build_pred_node_h(pB, vB, ldsh, lgl, W_att, batt, hB);

    const int op = op_ids[j];
    const float w1 = __expf(lgl[2*VOCABSZ + op]);
    const float inv2 = 1.0f / (w0 + w1 + w2);

    __syncthreads();   // all phase-1 table reads done: T/pe/ve regions dead

    // ---- stash hA -> fp16 LDS (overlays dead T region); hA regs die here ----
    {
        __half2* st = (__half2*)ldsh;           // [25][512]
#pragma unroll
        for (int i = 0; i < LDIM/2; ++i)
            st[i*512 + tid] = __floats2half2_rn(hA[2*i], hA[2*i+1]);
    }
    // ---- stage Tb+oe (fp16, contiguous 20000 B) into dead pe/ve region ----
    {
        const uint4* src = (const uint4*)((const __half*)ws + H_TB);   // 1250 uint4
        uint4* dst = (uint4*)(ldsh + 30000);
        for (int i = tid; i < 1250; i += 512) dst[i] = src[i];
    }
    __syncthreads();

    // ---- phase 2: lin2 = Tb[op] + hA @ Wbin[0:50] + hB @ Wbin[100:150] ----
    const __half2* stash = (const __half2*)ldsh;
    float lin2[LDIM];
    {
        const __half2* Tb2 = (const __half2*)(ldsh + 30000) + op*(LDIM/2);
#pragma unroll
        for (int i = 0; i < LDIM/2; ++i) {
            float2 t2 = __half22float2(Tb2[i]);
            lin2[2*i] = t2.x; lin2[2*i+1] = t2.y;
        }
    }
#pragma unroll
    for (int i = 0; i < LDIM/2; ++i) {
        const float2 a2 = __half22float2(stash[i*512 + tid]);
        const float b0 = hB[2*i], b1 = hB[2*i+1];
        const float* wa0 = W_bin + (2*i)*LDIM;               // uniform -> s_load stream
        const float* wa1 = W_bin + (2*i+1)*LDIM;
        const float* wb0 = W_bin + (2*LDIM + 2*i)*LDIM;
        const float* wb1 = W_bin + (2*LDIM + 2*i+1)*LDIM;
#pragma unroll
        for (int d = 0; d < LDIM; ++d)
            lin2[d] += a2.x*wa0[d] + a2.y*wa1[d] + b0*wb0[d] + b1*wb1[d];
    }

    // ---- h_bin = relu(lin2) + inv2*(w0*hA + w2*hB + w1*oe[op]) ----
    float h[LDIM];
    {
        const __half2* oe2 = (const __half2*)(ldsh + 35000) + op*(LDIM/2);
#pragma unroll
        for (int i = 0; i < LDIM/2; ++i) {
            float2 a2 = __half22float2(stash[i*512 + tid]);
            float2 o2 = __half22float2(oe2[i]);
            h[2*i]   = fmaxf(lin2[2*i],   0.0f) + (w0*a2.x + w2*hB[2*i]   + w1*o2.x)*inv2;
            h[2*i+1] = fmaxf(lin2[2*i+1], 0.0f) + (w0*a2.y + w2*hB[2*i+1] + w1*o2.y)*inv2;
        }
    }
    __syncthreads();   // stash + Tb/oe reads done: transpose overlay is now safe

    // ---- h_un = relu(h @ W_un + b_un); h_q = relu(h_un @ W_univ + b_univ) ----
    {
        float acc[LDIM];
#pragma unroll
        for (int d = 0; d < LDIM; ++d) acc[d] = b_un[d];
#pragma unroll
        for (int e = 0; e < LDIM; ++e) {
            const float he = h[e];
            const float* wr = W_un + e*LDIM;
#pragma unroll
            for (int d = 0; d < LDIM; ++d) acc[d] += he * wr[d];
        }
#pragma unroll
        for (int d = 0; d < LDIM; ++d) h[d] = fmaxf(acc[d], 0.0f);
    }
    {
        float acc[LDIM];
#pragma unroll
        for (int d = 0; d < LDIM; ++d) acc[d] = b_univ[d];
#pragma unroll
        for (int e = 0; e < LDIM; ++e) {
            const float he = h[e];
            const float* wr = W_univ + e*LDIM;
#pragma unroll
            for (int d = 0; d < LDIM; ++d) acc[d] += he * wr[d];
        }
#pragma unroll
        for (int d = 0; d < LDIM; ++d) h[d] = fmaxf(acc[d], 0.0f);
    }

    // ---- phase 3: out = h @ W_fin + b_fin, LDS-transposed coalesced stores
    //      (per-wave buffer overlaying dead stash/Tb regions; wave-synchronous)
    const int wave = tid >> 6, lane = tid & 63;
    float* sw = ldsf + wave * (64*33);          // 8 waves * 2112 fl = 16896 <= 20000
    const int rowbase = blockIdx.x*512 + wave*64;
    for (int c = 0; c < 5; ++c) {
        float acc[31];
        const int obase = c * 31;
#pragma unroll
        for (int o = 0; o < 31; ++o) acc[o] = b_fin[obase + o];
#pragma unroll
        for (int d = 0; d < LDIM; ++d) {
            const float hq = h[d];
            const float* wr = W_fin + d*ODIM + obase;
#pragma unroll
            for (int o = 0; o < 31; ++o) acc[o] += hq * wr[o];
        }
#pragma unroll
        for (int o = 0; o < 31; ++o) sw[lane*33 + o] = acc[o];
        float* gb = out + (size_t)rowbase * ODIM + obase;
#pragma unroll
        for (int it = 0; it < 31; ++it) {
            const int f = it*64 + lane;
            const int row = f / 31;
            const int col = f - row*31;
            gb[row*ODIM + col] = sw[row*33 + col];
        }
    }
}

// ---------------------------------------------------------------------------
extern "C" void kernel_launch(void* const* d_in, const int* in_sizes, int n_in,
                              void* d_out, int out_size, void* d_ws, size_t ws_size,
                              hipStream_t stream) {
    const float* pe     = (const float*)d_in[0];
    const float* ve     = (const float*)d_in[1];
    const float* oe     = (const float*)d_in[2];
    const float* W_pred = (const float*)d_in[3];
    const float* b_pred = (const float*)d_in[4];
    const float* W_bin  = (const float*)d_in[5];
    const float* b_bin  = (const float*)d_in[6];
    const float* W_un   = (const float*)d_in[7];
    const float* b_un   = (const float*)d_in[8];
    const float* W_univ = (const float*)d_in[9];
    const float* b_univ = (const float*)d_in[10];
    const float* W_att  = (const float*)d_in[11];
    const float* b_att  = (const float*)d_in[12];
    const float* W_fin  = (const float*)d_in[13];
    const float* b_fin  = (const float*)d_in[14];
    const int* pred_ids = (const int*)d_in[15];
    const int* var_ids  = (const int*)d_in[16];
    const int* op_ids   = (const int*)d_in[17];
    float* out = (float*)d_out;
    float* ws  = (float*)d_ws;

    precompute_kernel<<<1005, 64, 0, stream>>>(pe, ve, oe, W_pred, b_pred,
                                               W_bin, b_bin, W_att, b_att, ws);
    fused_kernel<<<MBIN/512, 512, 0, stream>>>(W_bin, W_un, b_un,
                                               W_univ, b_univ, W_att, b_att,
                                               W_fin, b_fin, pred_ids, var_ids,
                                               op_ids, ws, out);
}